// Round 11
// baseline (918.172 us; speedup 1.0000x reference)
//
#include <hip/hip_runtime.h>
#include <hip/hip_cooperative_groups.h>
#include <math.h>

namespace cg = cooperative_groups;

#define N_NODES 100000
#define N_EDGES 800000
#define F 128
#define SCAN_BLOCKS ((N_NODES + 255) / 256)   // 391
#define CSR_CAP (N_EDGES + 7 * N_NODES)       // 1.5M entries (8-padded worst case)

typedef __attribute__((ext_vector_type(8))) short short8;
typedef __attribute__((ext_vector_type(4))) float floatx4;

__device__ __forceinline__ unsigned short f2bf(float f) {
    unsigned u = __float_as_uint(f);
    u += 0x7fffu + ((u >> 16) & 1u);          // round-to-nearest-even
    return (unsigned short)(u >> 16);
}
__device__ __forceinline__ float bf_lo(unsigned u) { return __uint_as_float(u << 16); }
__device__ __forceinline__ float bf_hi(unsigned u) { return __uint_as_float(u & 0xffff0000u); }
__device__ __forceinline__ unsigned pack2(float a, float b) {
    return (unsigned)f2bf(a) | ((unsigned)f2bf(b) << 16);
}

// ---------------- hop phase (weight-free gather, 2 nodes/wave, exact 8-deep) ----------------
// acc = y[c] + sum y[r]; out = scale[c] * acc. Rows shifted +1; pad entries hit
// zero row 0 (L1-hot). Rows padded to x8 -> no predication, no tail.

__device__ __forceinline__ void hop_phase(const int* __restrict__ rowptr,
                                          const unsigned* __restrict__ csr,
                                          const float* __restrict__ scale,
                                          const uint2* __restrict__ src,
                                          uint2* __restrict__ dst,
                                          int tid, int nthreads) {
    int lane = tid & 63;
    int half = lane >> 5, off = lane & 31;
    int nwaves = nthreads >> 6;
    for (int wv = tid >> 6; wv < N_NODES / 2; wv += nwaves) {   // 50k units exact
        int node = wv * 2 + half;
        uint2 u = src[(size_t)(node + 1) * 32 + off];           // own (pre-scaled) row
        float a0 = bf_lo(u.x), a1 = bf_hi(u.x);
        float a2 = bf_lo(u.y), a3 = bf_hi(u.y);
        int e = rowptr[node], end = rowptr[node + 1];           // multiple of 8 apart
        for (; e < end; e += 8) {
            const uint4* cp = (const uint4*)(csr + e);          // 16B-aligned
            uint4 c0 = cp[0], c1 = cp[1];                       // 8 indices
            unsigned idx[8] = {c0.x, c0.y, c0.z, c0.w, c1.x, c1.y, c1.z, c1.w};
#pragma unroll
            for (int j = 0; j < 8; ++j) {
                uint2 v = src[(size_t)idx[j] * 32 + off];
                a0 += bf_lo(v.x); a1 += bf_hi(v.x);
                a2 += bf_lo(v.y); a3 += bf_hi(v.y);
            }
        }
        float s = scale[node];
        uint2 o; o.x = pack2(s * a0, s * a1); o.y = pack2(s * a2, s * a3);
        dst[(size_t)(node + 1) * 32 + off] = o;
    }
}

// ---------------- cooperative mega-kernel: zero/hist/scan/prep/fill/hop1/hop2 ----------------
// grid 1024 = 4 blocks/CU with margin (R10 failed: 1536 == exact max -> launch rejected)

__global__ __launch_bounds__(256, 4) void k_mega(const float4* __restrict__ x,
                                                 const int* __restrict__ row,
                                                 const int* __restrict__ col,
                                                 int* __restrict__ cnt,
                                                 int* __restrict__ rowptr,
                                                 int* __restrict__ bsum,
                                                 float* __restrict__ dinv,
                                                 float* __restrict__ dinv2,
                                                 unsigned* __restrict__ csr,
                                                 uint2* __restrict__ xb,
                                                 uint2* __restrict__ h1b) {
    cg::grid_group grid = cg::this_grid();
    __shared__ int s[256];
    const int T = (int)(gridDim.x * blockDim.x);
    const int tid = blockIdx.x * blockDim.x + threadIdx.x;
    const int t = threadIdx.x, b = blockIdx.x;

    // P0: zero cnt
    for (int i = tid; i < N_NODES; i += T) cnt[i] = 0;
    grid.sync();

    // P1: histogram + zero csr (pad slots) + zero row 0 of xb/h1b
    for (int e = tid; e < N_EDGES; e += T) atomicAdd(&cnt[col[e]], 1);
    for (int i = tid; i < CSR_CAP; i += T) csr[i] = 0;
    if (tid < 32) { xb[tid] = (uint2){0u, 0u}; h1b[tid] = (uint2){0u, 0u}; }
    grid.sync();

    // P2: block-local exclusive scan of padded counts; dinv & dinv^2
    if (b < SCAN_BLOCKS) {
        int i = b * 256 + t;
        int v = 0;
        if (i < N_NODES) {
            int c = cnt[i];
            float d = rsqrtf((float)c + 1.0f);       // +1 self-loop
            dinv[i] = d; dinv2[i] = d * d;
            v = (c + 7) & ~7;                        // pad row to multiple of 8
        }
        s[t] = v; __syncthreads();
#pragma unroll
        for (int off = 1; off < 256; off <<= 1) {
            int u = (t >= off) ? s[t - off] : 0;
            __syncthreads();
            s[t] += u; __syncthreads();
        }
        if (i <= N_NODES) rowptr[i] = s[t] - v;      // exclusive
        if (t == 255) bsum[b] = s[255];
    }
    grid.sync();

    // P3: finalize scan (per-block private prefix of bsum)
    if (b < SCAN_BLOCKS) {
        int p = 0;
        for (int k = t; k < b; k += 256) p += bsum[k];
        s[t] = p; __syncthreads();
#pragma unroll
        for (int off = 128; off; off >>= 1) {
            if (t < off) s[t] += s[t + off];
            __syncthreads();
        }
        int P = s[0];
        int i = b * 256 + t;
        if (i <= N_NODES) rowptr[i] += P;
    }
    grid.sync();

    // P4: fill CSR (scattered, consumes cnt) + prep xb = bf16(dinv*x) (streaming;
    // its traffic hides the fill's line-RMW latency)
    for (int e = tid; e < N_EDGES; e += T) {
        int r = row[e], c = col[e];
        int pos = rowptr[c] + atomicSub(&cnt[c], 1) - 1;
        csr[pos] = (unsigned)(r + 1);                // entry = src index + 1
    }
    for (int i = tid; i < N_NODES * 32; i += T) {
        int node = i >> 5;
        float d = dinv[node];
        float4 v = x[i];
        uint2 o; o.x = pack2(d * v.x, d * v.y); o.y = pack2(d * v.z, d * v.w);
        xb[i + 32] = o;                              // row node+1
    }
    grid.sync();

    // P5: hop 1 (xb -> h1b, scale dinv^2 -> y1)
    hop_phase(rowptr, csr, dinv2, xb, h1b, tid, T);
    grid.sync();

    // P6: hop 2 (h1b -> xb, scale dinv -> h2)
    hop_phase(rowptr, csr, dinv, h1b, xb, tid, T);
}

// ---------------- standalone fallback kernels (R9-validated path) ----------------

__global__ void k_hist(const int* __restrict__ col, int* __restrict__ cnt) {
    int e = blockIdx.x * blockDim.x + threadIdx.x;
    if (e < N_EDGES) atomicAdd(&cnt[col[e]], 1);
}

__global__ void k_scan1(const int* __restrict__ cnt, int* __restrict__ rowptr,
                        int* __restrict__ bsum, float* __restrict__ dinv,
                        float* __restrict__ dinv2) {
    __shared__ int s[256];
    int t = threadIdx.x, i = blockIdx.x * 256 + t;
    int v = 0;
    if (i < N_NODES) {
        int c = cnt[i];
        float d = rsqrtf((float)c + 1.0f);
        dinv[i] = d; dinv2[i] = d * d;
        v = (c + 7) & ~7;
    }
    s[t] = v; __syncthreads();
#pragma unroll
    for (int off = 1; off < 256; off <<= 1) {
        int u = (t >= off) ? s[t - off] : 0;
        __syncthreads();
        s[t] += u; __syncthreads();
    }
    if (i <= N_NODES) rowptr[i] = s[t] - v;
    if (t == 255) bsum[blockIdx.x] = s[255];
}

__global__ void k_scan3(int* __restrict__ rowptr, const int* __restrict__ bsum) {
    __shared__ int s[256];
    int b = blockIdx.x, t = threadIdx.x;
    int p = 0;
    for (int k = t; k < b; k += 256) p += bsum[k];
    s[t] = p; __syncthreads();
#pragma unroll
    for (int off = 128; off; off >>= 1) {
        if (t < off) s[t] += s[t + off];
        __syncthreads();
    }
    int P = s[0];
    int i = b * 256 + t;
    if (i <= N_NODES) rowptr[i] += P;
}

__global__ void k_prep(const float4* __restrict__ x, const float* __restrict__ dinv,
                       uint2* __restrict__ xb, uint2* __restrict__ h1b) {
    int i = blockIdx.x * blockDim.x + threadIdx.x;
    if (i < 32) { xb[i] = (uint2){0u, 0u}; h1b[i] = (uint2){0u, 0u}; }
    if (i >= N_NODES * 32) return;
    int node = i >> 5;
    float d = dinv[node];
    float4 v = x[i];
    uint2 o; o.x = pack2(d * v.x, d * v.y); o.y = pack2(d * v.z, d * v.w);
    xb[i + 32] = o;
}

__global__ void k_fill(const int* __restrict__ row, const int* __restrict__ col,
                       const int* __restrict__ rowptr, int* __restrict__ cnt,
                       unsigned* __restrict__ csr) {
    int e = blockIdx.x * blockDim.x + threadIdx.x;
    if (e >= N_EDGES) return;
    int r = row[e], c = col[e];
    int pos = rowptr[c] + atomicSub(&cnt[c], 1) - 1;
    csr[pos] = (unsigned)(r + 1);
}

__global__ __launch_bounds__(256) void k_hop(const int* __restrict__ rowptr,
                                             const unsigned* __restrict__ csr,
                                             const float* __restrict__ scale,
                                             const uint2* __restrict__ src,
                                             uint2* __restrict__ dst) {
    int tid = blockIdx.x * blockDim.x + threadIdx.x;
    hop_phase(rowptr, csr, scale, src, dst, tid, N_NODES / 2 * 64);
}

// ---------------- MFMA GEMM + bias + log_softmax ----------------

__global__ __launch_bounds__(256) void k_gemm_lsm_mfma(const unsigned short* __restrict__ h,
                                                       const float* __restrict__ W,
                                                       const float* __restrict__ b,
                                                       float* __restrict__ out) {
    int lane = threadIdx.x & 63;
    int wave = threadIdx.x >> 6;
    int m = lane & 15, quad = lane >> 4;

    // B fragment: lane holds B[k=quad*8+j][n=m] = W[16t+m][ks*32+quad*8+j]
    short8 bfr[8][4];
    float bv[8];
#pragma unroll
    for (int t = 0; t < 8; ++t) {
        bv[t] = b[16 * t + m];
        const float* wr = W + (size_t)(16 * t + m) * 128;
#pragma unroll
        for (int ks = 0; ks < 4; ++ks) {
            const float* wp = wr + ks * 32 + quad * 8;
            short8 v;
#pragma unroll
            for (int j = 0; j < 8; ++j) v[j] = (short)f2bf(wp[j]);
            bfr[t][ks] = v;
        }
    }

    const int ngroups = (N_NODES + 63) / 64;        // 1563 groups of 64 nodes
    for (int g = blockIdx.x; g < ngroups; g += gridDim.x) {
        int gbase = g * 64 + wave * 16;
        int nodeA = gbase + m;
        int node_c = nodeA < N_NODES ? nodeA : N_NODES - 1;
        short8 a[4];
#pragma unroll
        for (int ks = 0; ks < 4; ++ks)
            a[ks] = *(const short8*)(h + (size_t)node_c * 128 + ks * 32 + quad * 8);
        floatx4 acc[8];
#pragma unroll
        for (int t = 0; t < 8; ++t) acc[t] = (floatx4){bv[t], bv[t], bv[t], bv[t]};
#pragma unroll
        for (int ks = 0; ks < 4; ++ks)
#pragma unroll
            for (int t = 0; t < 8; ++t)
                acc[t] = __builtin_amdgcn_mfma_f32_16x16x32_bf16(a[ks], bfr[t][ks], acc[t], 0, 0, 0);

        // D layout: row = gbase + quad*4 + r, col = 16t + m
#pragma unroll
        for (int r = 0; r < 4; ++r) {
            float mx = acc[0][r];
#pragma unroll
            for (int t = 1; t < 8; ++t) mx = fmaxf(mx, acc[t][r]);
#pragma unroll
            for (int msk = 1; msk < 16; msk <<= 1) mx = fmaxf(mx, __shfl_xor(mx, msk));
            float sm = 0.f;
#pragma unroll
            for (int t = 0; t < 8; ++t) sm += __expf(acc[t][r] - mx);
#pragma unroll
            for (int msk = 1; msk < 16; msk <<= 1) sm += __shfl_xor(sm, msk);
            float l = mx + __logf(sm);
            int rown = gbase + quad * 4 + r;
            if (rown < N_NODES) {
                float* op = out + (size_t)rown * 128 + m;
#pragma unroll
                for (int t = 0; t < 8; ++t) op[16 * t] = acc[t][r] - l;
            }
        }
    }
}

// ---------------- launch ----------------

extern "C" void kernel_launch(void* const* d_in, const int* in_sizes, int n_in,
                              void* d_out, int out_size, void* d_ws, size_t ws_size,
                              hipStream_t stream) {
    const float4* x4 = (const float4*)d_in[0];
    const float* W = (const float*)d_in[1];
    const float* bb = (const float*)d_in[2];
    const int* edge = (const int*)d_in[3];
    const int* row = edge;             // source nodes j
    const int* col = edge + N_EDGES;   // target nodes i
    float* out = (float*)d_out;

    // workspace layout (4B word offsets); cnt adjacent to csr (fallback memset)
    int*      rowptr = (int*)d_ws;                    // 100k+1
    int*      bsum   = rowptr + 102400;               // 391
    float*    dinv   = (float*)(bsum + 1024);         // 100k
    float*    dinv2  = dinv + 102400;                 // 100k
    int*      cnt    = (int*)(dinv2 + 102400);        // 100k
    unsigned* csr    = (unsigned*)(cnt + 102400);     // 1.5M
    uint2*    xb     = (uint2*)(csr + CSR_CAP);       // (N+1)*32 uint2 = 25.6 MB
    uint2*    h1b    = xb + 32 * (N_NODES + 1);       // (N+1)*32 uint2

    void* args[] = {(void*)&x4, (void*)&row, (void*)&col, (void*)&cnt,
                    (void*)&rowptr, (void*)&bsum, (void*)&dinv, (void*)&dinv2,
                    (void*)&csr, (void*)&xb, (void*)&h1b};
    hipError_t rc = hipLaunchCooperativeKernel((void*)k_mega, dim3(1024), dim3(256),
                                               args, 0, stream);
    if (rc != hipSuccess) {
        // deterministic fallback: R9-validated 9-dispatch path
        int nb_edges = (N_EDGES + 255) / 256;
        int nb_prep = (N_NODES * 32 + 255) / 256;
        hipMemsetAsync(cnt, 0, (size_t)(102400 + CSR_CAP) * 4, stream);
        k_hist<<<nb_edges, 256, 0, stream>>>(col, cnt);
        k_scan1<<<SCAN_BLOCKS, 256, 0, stream>>>(cnt, rowptr, bsum, dinv, dinv2);
        k_scan3<<<SCAN_BLOCKS, 256, 0, stream>>>(rowptr, bsum);
        k_prep<<<nb_prep, 256, 0, stream>>>(x4, dinv, xb, h1b);
        k_fill<<<nb_edges, 256, 0, stream>>>(row, col, rowptr, cnt, csr);
        int hop_blocks = (N_NODES / 2 * 64) / 256;    // 12500
        k_hop<<<hop_blocks, 256, 0, stream>>>(rowptr, csr, dinv2, xb, h1b);
        k_hop<<<hop_blocks, 256, 0, stream>>>(rowptr, csr, dinv, h1b, xb);
    }

    // h2 lives in xb (rows shifted by 1 -> skip 32 uint2)
    k_gemm_lsm_mfma<<<512, 256, 0, stream>>>((const unsigned short*)(xb + 32), W, bb, out);
}